// Round 7
// baseline (205.928 us; speedup 1.0000x reference)
//
#include <hip/hip_runtime.h>

typedef unsigned short u16;
typedef unsigned int u32;
typedef __attribute__((ext_vector_type(8))) short short8;
typedef __attribute__((ext_vector_type(4))) float floatx4;

#define NUMS 2048
#define DIM 128
#define ROWS_TOT 16384
#define HALF_ROWS 8192
#define KTOP 129
#define SCALE 0.08838834764831845f
#define TC0 0x3F00u  // topk coarse window base (att=0.5); spacing 8, 8 thresholds

__device__ __forceinline__ u16 f2bf(float f) {
  u32 u = __builtin_bit_cast(u32, f);
  u += 0x7FFFu + ((u >> 16) & 1u);
  return (u16)(u >> 16);
}
__device__ __forceinline__ float bf2f(u32 b) {
  return __builtin_bit_cast(float, b << 16);
}

// weight fp32 [2048][128] -> wb bf16 [2048][128] + wt bf16 [128][2048]
__global__ void cvt_w_k(const float* __restrict__ w, u16* __restrict__ wb,
                        u16* __restrict__ wt) {
  __shared__ u16 tile[32][33];
  const int tx = threadIdx.x, ty = threadIdx.y;
  const int x = blockIdx.x * 32 + tx;
  const int y0 = blockIdx.y * 32;
#pragma unroll
  for (int j = 0; j < 32; j += 8) {
    const u16 v = f2bf(w[(size_t)(y0 + ty + j) * DIM + x]);
    wb[(size_t)(y0 + ty + j) * DIM + x] = v;
    tile[ty + j][tx] = v;
  }
  __syncthreads();
  const int x2 = y0 + tx;
  const int y2 = blockIdx.x * 32 + ty;
#pragma unroll
  for (int j = 0; j < 32; j += 8)
    wt[(size_t)(y2 + j) * NUMS + x2] = tile[tx][ty + j];
}

// GEMM1 + sigmoid + exact top-129 mean; att kept in registers.
// First-half rows also write att (bf16) to attG in fragment-native panel
// layout: elem(p, w, nt, m, q, e) = p*32768 + (w*16+nt)*256 + m*16 + q*4 + e
// -> each (w,nt) store instruction covers one contiguous 512 B block.
__global__ __launch_bounds__(512, 4)
void g1tk_k(const float* __restrict__ dataF, const u16* __restrict__ wb,
            u16* __restrict__ attG, float* __restrict__ out) {
  __shared__ __align__(16) u32 cntA[8][16][4];
  __shared__ __align__(16) u32 cntB[8][16][4];
  __shared__ float sumS[8][16];
  const int tid = threadIdx.x;
  const int r0 = blockIdx.x * 16;
  const int lane = tid & 63, wave = tid >> 6;
  const int m = lane & 15, q = lane >> 4;

  // B-operand fragments: data row r0+m, fp32 -> bf16 inline
  short8 dfrag[4];
  {
    const float* ap = dataF + (size_t)(r0 + m) * DIM + q * 8;
#pragma unroll
    for (int ks = 0; ks < 4; ks++) {
      const float4 x = *(const float4*)(ap + ks * 32);
      const float4 y = *(const float4*)(ap + ks * 32 + 4);
      short8 v;
      v[0] = (short)f2bf(x.x); v[1] = (short)f2bf(x.y);
      v[2] = (short)f2bf(x.z); v[3] = (short)f2bf(x.w);
      v[4] = (short)f2bf(y.x); v[5] = (short)f2bf(y.y);
      v[6] = (short)f2bf(y.z); v[7] = (short)f2bf(y.w);
      dfrag[ks] = v;
    }
  }

  // GEMM1 (transposed): lane holds data-row m, att-cols wave*256 + nt*16 + q*4 + {0..3}
  u32 pk[32];  // this lane's 64 bf16 att codes, packed 2/dword
  const bool wr = (r0 < HALF_ROWS);
  u16* ap0 = attG + (size_t)blockIdx.x * 32768 + wave * 4096 + m * 16 + q * 4;
#pragma unroll 4
  for (int nt = 0; nt < 16; nt++) {
    const int n0 = wave * 256 + nt * 16;
    const u16* wp = wb + (size_t)(n0 + m) * DIM + q * 8;
    floatx4 acc = {0.f, 0.f, 0.f, 0.f};
#pragma unroll
    for (int ks = 0; ks < 4; ks++) {
      const short8 wf = *(const short8*)(wp + ks * 32);
      acc = __builtin_amdgcn_mfma_f32_16x16x32_bf16(wf, dfrag[ks], acc, 0, 0, 0);
    }
    const float a0 = 1.f / (1.f + __expf(-acc[0] * SCALE));
    const float a1 = 1.f / (1.f + __expf(-acc[1] * SCALE));
    const float a2 = 1.f / (1.f + __expf(-acc[2] * SCALE));
    const float a3 = 1.f / (1.f + __expf(-acc[3] * SCALE));
    const u32 px = (u32)f2bf(a0) | ((u32)f2bf(a1) << 16);
    const u32 py = (u32)f2bf(a2) | ((u32)f2bf(a3) << 16);
    pk[2 * nt] = px;
    pk[2 * nt + 1] = py;
    if (wr) {
      uint2 p; p.x = px; p.y = py;
      *(uint2*)(ap0 + nt * 256) = p;  // contiguous 512 B per (wave,nt) instr
    }
  }
#pragma unroll
  for (int i = 0; i < 32; i++) pk[i] |= 0x80008000u;  // SWAR fold (codes < 0x8000)

  // per-lane count of (code >= t) over its 64 values
  auto cnt_ge = [&](u32 t) -> u32 {
    const u32 t2 = t * 0x10001u;
    u32 c = 0;
#pragma unroll
    for (int i = 0; i < 32; i++) c += __popc((pk[i] - t2) & 0x80008000u);
    return c;
  };

  // ---- coarse: 8 thresholds TC0 + 8j; reduce over q (shfl) then waves (LDS) ----
  u32 pk4[4];
  {
    u32 c8[8];
#pragma unroll
    for (int j = 0; j < 8; j++) c8[j] = cnt_ge(TC0 + 8u * (u32)j);
#pragma unroll
    for (int j = 0; j < 4; j++) pk4[j] = c8[2 * j] | (c8[2 * j + 1] << 16);
  }
#pragma unroll
  for (int j = 0; j < 4; j++) {
    pk4[j] += (u32)__shfl_xor((int)pk4[j], 16);
    pk4[j] += (u32)__shfl_xor((int)pk4[j], 32);
  }
  if (lane < 16) *(uint4*)&cntA[wave][m][0] = *(uint4*)pk4;
  __syncthreads();

  u32 cw[8];
  {
    u32 a4[4] = {0u, 0u, 0u, 0u};
#pragma unroll
    for (int w = 0; w < 8; w++) {
      const uint4 t = *(const uint4*)&cntA[w][m][0];
      a4[0] += t.x; a4[1] += t.y; a4[2] += t.z; a4[3] += t.w;
    }
#pragma unroll
    for (int j = 0; j < 4; j++) {
      cw[2 * j] = a4[j] & 0xFFFFu;
      cw[2 * j + 1] = a4[j] >> 16;
    }
  }
  const int bad = (cw[0] < KTOP || cw[7] >= KTOP) ? 1 : 0;
  const int anybad = __syncthreads_or(bad);

  u32 lo, cgt;
  if (anybad) {
    // block-level binary search (cold path; barrier-balanced, per-row via m)
    u32 L = 0u, H = 0x3F81u, cHv = 0u;
    for (int it = 0; it < 14; ++it) {
      if (H - L > 1u) {  // uniform across q and waves for a given m
        const u32 mid = (L + H) >> 1;
        u32 c = cnt_ge(mid);
        c += (u32)__shfl_xor((int)c, 16);
        c += (u32)__shfl_xor((int)c, 32);
        __syncthreads();
        if (lane < 16) cntA[wave][m][0] = c;
        __syncthreads();
        u32 cb = 0;
#pragma unroll
        for (int w = 0; w < 8; w++) cb += cntA[w][m][0];
        if (cb >= KTOP) L = mid; else { H = mid; cHv = cb; }
      } else {
        __syncthreads();
        __syncthreads();
      }
    }
    lo = L; cgt = cHv;
  } else {
    u32 ii = 0;  // bracket: last coarse threshold with count >= K
#pragma unroll
    for (int j = 1; j < 8; j++) ii += (cw[j] >= KTOP) ? 1u : 0u;
    const u32 B = TC0 + 8u * ii;
    u32 cB = cw[0];
#pragma unroll
    for (int j = 1; j < 8; j++) if (cw[j] >= KTOP) cB = cw[j];
    u32 cNext = 0u;  // count at B+8
#pragma unroll
    for (int j = 7; j >= 1; j--) if (cw[j] < KTOP) cNext = cw[j];

    // fine: 7 consecutive codes B+1..B+7
    u32 f4[4];
    {
      u32 c7[7];
#pragma unroll
      for (int j = 0; j < 7; j++) c7[j] = cnt_ge(B + 1u + (u32)j);
      f4[0] = c7[0] | (c7[1] << 16);
      f4[1] = c7[2] | (c7[3] << 16);
      f4[2] = c7[4] | (c7[5] << 16);
      f4[3] = c7[6];
    }
#pragma unroll
    for (int j = 0; j < 4; j++) {
      f4[j] += (u32)__shfl_xor((int)f4[j], 16);
      f4[j] += (u32)__shfl_xor((int)f4[j], 32);
    }
    if (lane < 16) *(uint4*)&cntB[wave][m][0] = *(uint4*)f4;
    __syncthreads();

    u32 cc[9];
    {
      u32 b4[4] = {0u, 0u, 0u, 0u};
#pragma unroll
      for (int w = 0; w < 8; w++) {
        const uint4 t = *(const uint4*)&cntB[w][m][0];
        b4[0] += t.x; b4[1] += t.y; b4[2] += t.z; b4[3] += t.w;
      }
      cc[0] = cB;
      cc[1] = b4[0] & 0xFFFFu; cc[2] = b4[0] >> 16;
      cc[3] = b4[1] & 0xFFFFu; cc[4] = b4[1] >> 16;
      cc[5] = b4[2] & 0xFFFFu; cc[6] = b4[2] >> 16;
      cc[7] = b4[3] & 0xFFFFu; cc[8] = cNext;
    }
    u32 jj = 0;
#pragma unroll
    for (int j = 1; j < 8; j++) jj += (cc[j] >= KTOP) ? 1u : 0u;
    lo = B + jj;
    cgt = cc[8];
#pragma unroll
    for (int j = 7; j >= 1; j--) if (cc[j] < KTOP) cgt = cc[j];
  }
  const float vstar = bf2f(lo);

  // exact top-K sum: sum(vals > v*) + (K - cnt_gt) * v*
  float s = 0.f;
#pragma unroll
  for (int i = 0; i < 32; i++) {
    const u32 cl = pk[i] & 0x7FFFu;
    const u32 ch = (pk[i] >> 16) & 0x7FFFu;
    if (cl > lo) s += bf2f(cl);
    if (ch > lo) s += bf2f(ch);
  }
  s += __shfl_xor(s, 16);
  s += __shfl_xor(s, 32);
  __syncthreads();
  if (lane < 16) sumS[wave][m] = s;
  __syncthreads();
  if (wave == 0 && lane < 16) {
    float st = 0.f;
#pragma unroll
    for (int w = 0; w < 8; w++) st += sumS[w][lane];
    const float mean = (st + (float)(KTOP - (int)cgt) * vstar) * (1.f / (float)KTOP);
    out[r0 + lane] = 1.f - mean;
  }
}

// GEMM2: augment = att[0:8192] @ W, att read from panel layout (contiguous
// 1 KB per ks-step per wave). M=32, N=64 per block; + data copy on by==0.
__global__ __launch_bounds__(256, 4)
void gemm2_k(const u16* __restrict__ attG, const u16* __restrict__ wt,
             const float* __restrict__ dataF, float* __restrict__ out) {
  const int tid = threadIdx.x;
  const int lane = tid & 63, wave = tid >> 6;
  const int m = lane & 15, q = lane >> 4;
  const int r0 = blockIdx.x * 32;

  if (blockIdx.y == 0) {  // copy fp32 data -> read_query[:, :128]
#pragma unroll
    for (int it = 0; it < 4; it++) {
      const int idx = it * 256 + tid;
      const int row = idx >> 5;
      const int c4 = (idx & 31) << 2;
      *(float4*)(out + 16384 + (size_t)(r0 + row) * 256 + c4) =
          *(const float4*)(dataF + (size_t)(r0 + row) * DIM + c4);
    }
  }

  const int ncol = blockIdx.y * 64 + wave * 16;
  const u16* ap = wt + (size_t)(ncol + m) * NUMS + q * 8;  // A: out-col ncol+m
  // B: att row (panel p, row m), k-cols ks*32 + q*8 + {0..7} in panel layout
  const u16* b0 = attG + (size_t)(blockIdx.x * 2) * 32768 +
                  (q >> 1) * 256 + (q & 1) * 8 + m * 16;
  const u16* b1 = b0 + 32768;  // panel p+1 (rows r0+16..r0+31)
  floatx4 a0 = {0.f, 0.f, 0.f, 0.f}, a1 = {0.f, 0.f, 0.f, 0.f};
#pragma unroll 8
  for (int ks = 0; ks < 64; ks++) {
    const short8 a = *(const short8*)(ap + ks * 32);
    a0 = __builtin_amdgcn_mfma_f32_16x16x32_bf16(a, *(const short8*)(b0 + ks * 512), a0, 0, 0, 0);
    a1 = __builtin_amdgcn_mfma_f32_16x16x32_bf16(a, *(const short8*)(b1 + ks * 512), a1, 0, 0, 0);
  }
  float4 s0, s1;
  s0.x = a0[0]; s0.y = a0[1]; s0.z = a0[2]; s0.w = a0[3];
  s1.x = a1[0]; s1.y = a1[1]; s1.z = a1[2]; s1.w = a1[3];
  *(float4*)(out + 16384 + (size_t)(r0 + m) * 256 + 128 + ncol + q * 4) = s0;
  *(float4*)(out + 16384 + (size_t)(r0 + 16 + m) * 256 + 128 + ncol + q * 4) = s1;
}

extern "C" void kernel_launch(void* const* d_in, const int* in_sizes, int n_in,
                              void* d_out, int out_size, void* d_ws, size_t ws_size,
                              hipStream_t stream) {
  const float* data = (const float*)d_in[0];    // [32,512,128] fp32
  const float* weight = (const float*)d_in[1];  // [2048,128] fp32
  float* out = (float*)d_out;  // 16384 mem_score + 16*512*256 read_query (fp32)

  u16* attG = (u16*)d_ws;                            // [512 panels][32768] bf16, 32 MiB
  u16* wt = attG + (size_t)HALF_ROWS * NUMS;         // [128][2048] bf16, 512 KiB
  u16* wb = wt + (size_t)NUMS * DIM;                 // [2048][128] bf16, 512 KiB

  cvt_w_k<<<dim3(DIM / 32, NUMS / 32), dim3(32, 8), 0, stream>>>(weight, wb, wt);
  g1tk_k<<<dim3(ROWS_TOT / 16), dim3(512), 0, stream>>>(data, wb, attG, out);
  gemm2_k<<<dim3(HALF_ROWS / 32, 2), dim3(256), 0, stream>>>(attG, wt, data, out);
}

// Round 8
// 168.758 us; speedup vs baseline: 1.2203x; 1.2203x over previous
//
#include <hip/hip_runtime.h>

typedef unsigned short u16;
typedef unsigned int u32;
typedef __attribute__((ext_vector_type(8))) short short8;
typedef __attribute__((ext_vector_type(4))) float floatx4;

#define NUMS 2048
#define DIM 128
#define ROWS_TOT 16384
#define HALF_ROWS 8192
#define KTOP 129
#define SCALE 0.08838834764831845f
#define TC0 0x3F00u  // topk window base (att=0.5); 8 thresholds spaced 8 codes

__device__ __forceinline__ u16 f2bf(float f) {
  u32 u = __builtin_bit_cast(u32, f);
  u += 0x7FFFu + ((u >> 16) & 1u);
  return (u16)(u >> 16);
}
__device__ __forceinline__ float bf2f(u32 b) {
  return __builtin_bit_cast(float, b << 16);
}

// weight fp32 [2048][128] -> wb bf16 [2048][128] + wt bf16 [128][2048]
__global__ void cvt_w_k(const float* __restrict__ w, u16* __restrict__ wb,
                        u16* __restrict__ wt) {
  __shared__ u16 tile[32][33];
  const int tx = threadIdx.x, ty = threadIdx.y;
  const int x = blockIdx.x * 32 + tx;
  const int y0 = blockIdx.y * 32;
#pragma unroll
  for (int j = 0; j < 32; j += 8) {
    const u16 v = f2bf(w[(size_t)(y0 + ty + j) * DIM + x]);
    wb[(size_t)(y0 + ty + j) * DIM + x] = v;
    tile[ty + j][tx] = v;
  }
  __syncthreads();
  const int x2 = y0 + tx;
  const int y2 = blockIdx.x * 32 + ty;
#pragma unroll
  for (int j = 0; j < 32; j += 8)
    wt[(size_t)(y2 + j) * NUMS + x2] = tile[tx][ty + j];
}

// One block = 16 data rows. GEMM1 -> LDS S (XOR-swizzled bf16) -> GEMM2 + topk.
// No global att round trip: WRITE should be ~logical output only.
__global__ __launch_bounds__(512, 4)
void fused_k(const float* __restrict__ dataF, const u16* __restrict__ wb,
             const u16* __restrict__ wt, float* __restrict__ out) {
  __shared__ u16 S[16 * NUMS];  // 64 KiB; S[row][chunk^row] 8-elem chunk swizzle
  const int tid = threadIdx.x;
  const int r0 = blockIdx.x * 16;
  const int lane = tid & 63, wave = tid >> 6;  // 8 waves
  const int m = lane & 15, q = lane >> 4;

  // ---- B-operand fragments: data row r0+m, fp32 -> bf16 inline ----
  short8 dfrag[4];
  {
    const float* ap = dataF + (size_t)(r0 + m) * DIM + q * 8;
#pragma unroll
    for (int ks = 0; ks < 4; ks++) {
      const float4 x = *(const float4*)(ap + ks * 32);
      const float4 y = *(const float4*)(ap + ks * 32 + 4);
      short8 v;
      v[0] = (short)f2bf(x.x); v[1] = (short)f2bf(x.y);
      v[2] = (short)f2bf(x.z); v[3] = (short)f2bf(x.w);
      v[4] = (short)f2bf(y.x); v[5] = (short)f2bf(y.y);
      v[6] = (short)f2bf(y.z); v[7] = (short)f2bf(y.w);
      dfrag[ks] = v;
    }
  }

  // ---- GEMM1 (transposed): lane holds data-row m, att-cols n0+q*4+{0..3} ----
#pragma unroll 4
  for (int nt = 0; nt < 16; nt++) {
    const int n0 = wave * 256 + nt * 16;
    const u16* wp = wb + (size_t)(n0 + m) * DIM + q * 8;
    floatx4 acc = {0.f, 0.f, 0.f, 0.f};
#pragma unroll
    for (int ks = 0; ks < 4; ks++) {
      const short8 wf = *(const short8*)(wp + ks * 32);
      acc = __builtin_amdgcn_mfma_f32_16x16x32_bf16(wf, dfrag[ks], acc, 0, 0, 0);
    }
    const float a0 = 1.f / (1.f + __expf(-acc[0] * SCALE));
    const float a1 = 1.f / (1.f + __expf(-acc[1] * SCALE));
    const float a2 = 1.f / (1.f + __expf(-acc[2] * SCALE));
    const float a3 = 1.f / (1.f + __expf(-acc[3] * SCALE));
    uint2 p;
    p.x = (u32)f2bf(a0) | ((u32)f2bf(a1) << 16);
    p.y = (u32)f2bf(a2) | ((u32)f2bf(a3) << 16);
    // logical chunk = n0/8 + (q>>1); physical = chunk ^ m; in-chunk off (q&1)*4
    const int chunk = wave * 32 + nt * 2 + (q >> 1);
    *(uint2*)(S + m * NUMS + ((chunk ^ m) << 3) + (q & 1) * 4) = p;
  }
  __syncthreads();

  // ---- first half: read_query = [data_fp32 | attention @ W] ----
  if (r0 < HALF_ROWS) {
    {  // copy fp32 data -> read_query[:, :128]; 512 thr x 16 B = 8 KB
      const int row = tid >> 5;
      const int c4 = (tid & 31) << 2;
      *(float4*)(out + 16384 + (size_t)(r0 + row) * 256 + c4) =
          *(const float4*)(dataF + (size_t)(r0 + row) * DIM + c4);
    }
    // GEMM2: A = wt rows (out-cols), B = S rows. Each wave owns 16 out-cols.
    const int n0 = wave * 16;
    const u16* ap = wt + (size_t)(n0 + m) * NUMS + q * 8;
    const u16* sb = S + m * NUMS;
    floatx4 acc = {0.f, 0.f, 0.f, 0.f};
#pragma unroll 8
    for (int ks = 0; ks < 64; ks++) {
      const short8 a = *(const short8*)(ap + ks * 32);  // imm offsets ks*64 B
      const short8 b = *(const short8*)(sb + (((ks * 4 + q) ^ m) << 3));
      acc = __builtin_amdgcn_mfma_f32_16x16x32_bf16(a, b, acc, 0, 0, 0);
    }
    // lane: data-row m, out-cols n0+q*4+{0..3} -> one dwordx4 store
    float4 st;
    st.x = acc[0]; st.y = acc[1]; st.z = acc[2]; st.w = acc[3];
    *(float4*)(out + 16384 + (size_t)(r0 + m) * 256 + 128 + n0 + q * 4) = st;
  }

  // ---- top-129 mean per row (2 rows per wave, fully in-wave) ----
#pragma unroll
  for (int rv = 0; rv < 2; rv++) {
    const int rr = wave * 2 + rv;
    // load 32 codes/lane as 4 b128 in PHYSICAL chunk order (swizzle-agnostic)
    u32 xh[16];
#pragma unroll
    for (int j = 0; j < 4; j++) {
      const uint4 t = *(const uint4*)(S + rr * NUMS + (j * 64 + lane) * 8);
      xh[j * 4 + 0] = t.x; xh[j * 4 + 1] = t.y;
      xh[j * 4 + 2] = t.z; xh[j * 4 + 3] = t.w;
    }
#pragma unroll
    for (int i = 0; i < 16; i++) xh[i] |= 0x80008000u;  // SWAR fold

    // per-lane count of (code >= t) over its 32 values
    auto cnt_ge_lane = [&](u32 t) -> u32 {
      const u32 t2 = t * 0x10001u;
      u32 c = 0;
#pragma unroll
      for (int i = 0; i < 16; i++) c += __popc((xh[i] - t2) & 0x80008000u);
      return c;
    };
    // wave-reduced count (6-step shfl)
    auto cnt_ge = [&](u32 t) -> u32 {
      u32 c = cnt_ge_lane(t);
#pragma unroll
      for (int off = 1; off < 64; off <<= 1) c += (u32)__shfl_xor((int)c, off);
      return c;
    };

    // window: 8 independent thresholds TC0+8j, one packed reduce
    u32 pk4[4];
    {
      u32 c8[8];
#pragma unroll
      for (int j = 0; j < 8; j++) c8[j] = cnt_ge_lane(TC0 + 8u * (u32)j);
#pragma unroll
      for (int j = 0; j < 4; j++) pk4[j] = c8[2 * j] | (c8[2 * j + 1] << 16);
    }
#pragma unroll
    for (int off = 1; off < 64; off <<= 1) {
#pragma unroll
      for (int j = 0; j < 4; j++) pk4[j] += (u32)__shfl_xor((int)pk4[j], off);
    }
    u32 cw[8];
#pragma unroll
    for (int j = 0; j < 4; j++) {
      cw[2 * j] = pk4[j] & 0xFFFFu;
      cw[2 * j + 1] = pk4[j] >> 16;
    }

    u32 lo, cgt;
    if (cw[0] >= KTOP && cw[7] < KTOP) {  // 129th code inside window (hot path)
      u32 ii = 0;
#pragma unroll
      for (int j = 1; j < 8; j++) ii += (cw[j] >= KTOP) ? 1u : 0u;
      const u32 B = TC0 + 8u * ii;
      u32 cB = cw[ii];          // count at B (>= K)
      u32 cNext = cw[7];        // count at B+8 (< K) -- ii<=6 here
#pragma unroll
      for (int j = 7; j >= 1; j--) if (cw[j] < KTOP) cNext = cw[j];
      // fine: 7 consecutive codes B+1..B+7, one packed reduce
      u32 f4[4];
      {
        u32 c7[7];
#pragma unroll
        for (int j = 0; j < 7; j++) c7[j] = cnt_ge_lane(B + 1u + (u32)j);
        f4[0] = c7[0] | (c7[1] << 16);
        f4[1] = c7[2] | (c7[3] << 16);
        f4[2] = c7[4] | (c7[5] << 16);
        f4[3] = c7[6];
      }
#pragma unroll
      for (int off = 1; off < 64; off <<= 1) {
#pragma unroll
        for (int j = 0; j < 4; j++) f4[j] += (u32)__shfl_xor((int)f4[j], off);
      }
      u32 cc[9];
      cc[0] = cB;
      cc[1] = f4[0] & 0xFFFFu; cc[2] = f4[0] >> 16;
      cc[3] = f4[1] & 0xFFFFu; cc[4] = f4[1] >> 16;
      cc[5] = f4[2] & 0xFFFFu; cc[6] = f4[2] >> 16;
      cc[7] = f4[3] & 0xFFFFu; cc[8] = cNext;
      u32 jj = 0;
#pragma unroll
      for (int j = 1; j < 8; j++) jj += (cc[j] >= KTOP) ? 1u : 0u;
      lo = B + jj;
      cgt = cc[8];
#pragma unroll
      for (int j = 7; j >= 1; j--) if (cc[j] < KTOP) cgt = cc[j];
    } else {  // exact per-wave secant/bisect fallback (r6-verified; cold)
      u32 L = 0u, cL = 2048u, H = 0x3F81u, cH = 0u;
      u32 t = 0x3F05u;
      for (int it = 0; it < 24 && H - L > 1u; ++it) {
        const u32 c = cnt_ge(t);
        if (c >= KTOP) { L = t; cL = c; } else { H = t; cH = c; }
        if (H - L <= 1u) break;
        u32 tn;
        if (it < 3) tn = L + ((cL - KTOP) * (H - L)) / (cL - cH);
        else tn = (L + H) >> 1;
        if (tn <= L) tn = L + 1u;
        if (tn >= H) tn = H - 1u;
        t = tn;
      }
      lo = L;
      cgt = cH;  // count at H == lo+1 at termination
    }

    // exact top-K sum: sum(vals > v*) + (K - cgt) * v*
    const float vstar = bf2f(lo);
    float s = 0.f;
#pragma unroll
    for (int i = 0; i < 16; i++) {
      const u32 cl = xh[i] & 0x7FFFu;          // recover raw codes
      const u32 ch = (xh[i] >> 16) & 0x7FFFu;
      if (cl > lo) s += bf2f(cl);
      if (ch > lo) s += bf2f(ch);
    }
#pragma unroll
    for (int off = 1; off < 64; off <<= 1) s += __shfl_xor(s, off);
    if (lane == 0) {
      const float mean = (s + (float)(KTOP - (int)cgt) * vstar) * (1.f / (float)KTOP);
      out[r0 + rr] = 1.f - mean;
    }
  }
}

extern "C" void kernel_launch(void* const* d_in, const int* in_sizes, int n_in,
                              void* d_out, int out_size, void* d_ws, size_t ws_size,
                              hipStream_t stream) {
  const float* data = (const float*)d_in[0];    // [32,512,128] fp32
  const float* weight = (const float*)d_in[1];  // [2048,128] fp32
  float* out = (float*)d_out;  // 16384 mem_score + 16*512*256 read_query (fp32)

  u16* wt = (u16*)d_ws;       // [128][2048] bf16, 512 KiB
  u16* wb = wt + NUMS * DIM;  // [2048][128] bf16, 512 KiB

  cvt_w_k<<<dim3(DIM / 32, NUMS / 32), dim3(32, 8), 0, stream>>>(weight, wb, wt);
  fused_k<<<dim3(ROWS_TOT / 16), dim3(512), 0, stream>>>(data, wb, wt, out);
}